// Round 13
// baseline (1299.401 us; speedup 1.0000x reference)
//
#include <hip/hip_runtime.h>
#include <hip/hip_bf16.h>
#include <stdint.h>

// ---------------------------------------------------------------------------
// Alignment_49735721287759: CLIP-style alignment head on MI355X (gfx950)
// Round 13 = round-12 (best, 1238us) + reuse-optimized k_scores:
//  - all 32 score vectors staged in LDS per block; token rows read ONCE
//    (was 32x re-read = ~570 MB redundant traffic).
//  - arithmetic is BITWISE IDENTICAL to round 12 (same lane mapping, same
//    shfl tree) -> top-k selection provably unchanged.
// Everything else (GEMM engine, LN folding, attn, gather) unchanged.
// ---------------------------------------------------------------------------

typedef __attribute__((ext_vector_type(8))) short short8;
typedef __attribute__((ext_vector_type(4))) float f32x4;

__device__ __forceinline__ float bf2f(short u) {
    return __uint_as_float(((uint32_t)(uint16_t)u) << 16);
}
__device__ __forceinline__ unsigned short f2bf(float f) {
    __hip_bfloat16 h = __float2bfloat16(f);
    return *reinterpret_cast<unsigned short*>(&h);
}
__device__ __forceinline__ void gload16(const void* g, void* l) {
    __builtin_amdgcn_global_load_lds(
        (const __attribute__((address_space(1))) unsigned int*)g,
        (__attribute__((address_space(3))) unsigned int*)l, 16, 0, 0);
}

// ---------------- fused f32 -> bf16 convert; Wkv columns scaled by ln2_w -----
__global__ __launch_bounds__(256) void k_f2b4(const float* __restrict__ s0,
                                              const float* __restrict__ s1,
                                              const float* __restrict__ s2,
                                              const float* __restrict__ s3,
                                              const float* __restrict__ ln2w,
                                              unsigned short* __restrict__ out) {
    for (int i = blockIdx.x * 256 + threadIdx.x; i < 6291456; i += gridDim.x * 256) {
        float v;
        if (i < 1572864) {
            v = s0[i];
            int rem = i % 786432;            // within layer: r*512+c
            if (rem >= 262144) {             // rows 512..1535 = K,V
                int l = i / 786432;
                v *= ln2w[l * 512 + (i & 511)];
            }
        } else if (i < 2097152) v = s1[i - 1572864];
        else if (i < 4194304) v = s2[i - 2097152];
        else v = s3[i - 4194304];
        out[i] = f2bf(v);
    }
}

// ---------------- effective kv bias: b2eff[l][n] = ln2_b_l . Wkv_l[n,:] + bkv
__global__ __launch_bounds__(256) void k_bias2(const float* __restrict__ in_proj_w,
                                               const float* __restrict__ in_proj_b,
                                               const float* __restrict__ ln2_b,
                                               float* __restrict__ b2eff) {
    int gid = blockIdx.x * 4 + (threadIdx.x >> 6);  // 0..2047
    int l = gid >> 10, o = gid & 1023;
    int lane = threadIdx.x & 63;
    const float* wr = in_proj_w + ((size_t)l * 1536 + 512 + o) * 512 + lane * 8;
    const float* b2 = ln2_b + l * 512 + lane * 8;
    float acc = 0.f;
#pragma unroll
    for (int e = 0; e < 8; e++) acc += wr[e] * b2[e];
#pragma unroll
    for (int off = 32; off; off >>= 1) acc += __shfl_xor(acc, off);
    if (lane == 0) b2eff[l * 1024 + o] = acc + in_proj_b[l * 1536 + 512 + o];
}

// ---------------- row L2 normalize (512-wide rows) ----------------
__global__ __launch_bounds__(256) void k_l2norm(const float* __restrict__ in,
                                                float* __restrict__ out) {
    size_t row = blockIdx.x;
    const float* x = in + row * 512;
    int t = threadIdx.x;
    float a0 = x[t], a1 = x[t + 256];
    float ss = a0 * a0 + a1 * a1;
#pragma unroll
    for (int off = 32; off; off >>= 1) ss += __shfl_xor(ss, off);
    __shared__ float s4[4];
    if ((t & 63) == 0) s4[t >> 6] = ss;
    __syncthreads();
    float tot = s4[0] + s4[1] + s4[2] + s4[3];
    float inv = 1.0f / sqrtf(tot);
    out[row * 512 + t] = a0 * inv;
    out[row * 512 + t + 256] = a1 * inv;
}

// ---------------- column sum over tokens (optionally masked) ----------------
__global__ __launch_bounds__(512) void k_colsum(const float* __restrict__ tok,
                                                const int* __restrict__ mask,
                                                float* __restrict__ out, int R) {
    int b = blockIdx.x;
    int d = threadIdx.x;  // 512 threads
    float acc = 0.f;
    for (int r = 0; r < R; r++) {
        float m = mask ? (float)mask[b * R + r] : 1.f;
        acc += m * tok[((size_t)b * R + r) * 512 + d];
    }
    out[b * 512 + d] = acc;
}

// ---------------- factored scores, token-rows read once ----------------------
// grid = 32 token-batches x 8 row-chunks. All 32 vecs staged in LDS (64KB).
// Per (row, v): BITWISE-identical arithmetic to the old k_scores
// (d = lane + c*64 ascending, shfl_xor 32..1, lane-0 write).
// swap=0 (img): out[(tb*32+v)*R + r];  swap=1 (txt): out[(v*32+tb)*R + r].
__global__ __launch_bounds__(256) void k_scores(const float* __restrict__ tok,
                                                const float* __restrict__ vec,
                                                float* __restrict__ out, int R,
                                                int rows_per, int swap) {
    __shared__ float sv[16384];  // 32 vecs x 512 f32
    int b = blockIdx.x;
    int tb = b >> 3, chunk = b & 7;
    for (int e = threadIdx.x; e < 16384; e += 256) sv[e] = vec[e];
    __syncthreads();
    int r0 = chunk * rows_per;
    int rend = r0 + rows_per;
    if (rend > R) rend = R;
    int wv = threadIdx.x >> 6, lane = threadIdx.x & 63;
    for (int r = r0 + wv; r < rend; r += 4) {
        const float* tr = tok + ((size_t)tb * R + r) * 512;
        float t8[8];
#pragma unroll
        for (int c = 0; c < 8; c++) t8[c] = tr[lane + c * 64];
        for (int v = 0; v < 32; v++) {
            const float* vv = sv + v * 512;
            float acc = 0.f;
#pragma unroll
            for (int c = 0; c < 8; c++) acc += t8[c] * vv[lane + c * 64];
#pragma unroll
            for (int off = 32; off; off >>= 1) acc += __shfl_xor(acc, off);
            if (lane == 0) {
                int pair = swap ? (v * 32 + tb) : (tb * 32 + v);
                out[(size_t)pair * R + r] = acc;
            }
        }
    }
}

// ---------------- top-16 (values desc, ties -> lowest idx), output sorted asc
__global__ __launch_bounds__(64) void k_topk(const float* __restrict__ simg,
                                             const float* __restrict__ stxt,
                                             int* __restrict__ idx_i, int* __restrict__ idx_t) {
    int bid = blockIdx.x;  // 0..2047: first 1024 img (n=196), then txt (n=77)
    bool isimg = bid < 1024;
    int ij = isimg ? bid : bid - 1024;
    const float* s = isimg ? simg + (size_t)ij * 196 : stxt + (size_t)ij * 77;
    int n = isimg ? 196 : 77;
    int* out = (isimg ? idx_i : idx_t) + ij * 16;
    int lane = threadIdx.x;
    float v[4];
    int ids[4];
#pragma unroll
    for (int k = 0; k < 4; k++) {
        int id = lane + k * 64;
        ids[k] = id;
        v[k] = (id < n) ? s[id] : -3.0e38f;
    }
    __shared__ int sel[16];
    for (int r = 0; r < 16; r++) {
        float bv = v[0];
        int bi = ids[0];
#pragma unroll
        for (int k = 1; k < 4; k++)
            if (v[k] > bv) { bv = v[k]; bi = ids[k]; }
#pragma unroll
        for (int off = 32; off; off >>= 1) {
            float ov = __shfl_xor(bv, off);
            int oi = __shfl_xor(bi, off);
            if (ov > bv || (ov == bv && oi < bi)) { bv = ov; bi = oi; }
        }
        if (lane == 0) sel[r] = bi;
#pragma unroll
        for (int k = 0; k < 4; k++)
            if (ids[k] == bi) v[k] = -3.0e38f;
    }
    if (lane == 0) {
        for (int a = 1; a < 16; a++) {
            int key = sel[a];
            int b = a - 1;
            while (b >= 0 && sel[b] > key) { sel[b + 1] = sel[b]; b--; }
            sel[b + 1] = key;
        }
        for (int a = 0; a < 16; a++) out[a] = sel[a];
    }
}

// ---------------- gather + fused row-stats normalization ---------------------
__global__ __launch_bounds__(64) void k_gather(const float* __restrict__ img_n,
                                               const float* __restrict__ txt_n,
                                               const float* __restrict__ img_feat,
                                               const float* __restrict__ txt_feat,
                                               const float* __restrict__ img_cls,
                                               const float* __restrict__ txt_cls,
                                               const int* __restrict__ idx_i,
                                               const int* __restrict__ idx_t,
                                               const float* __restrict__ ln1w0,
                                               const float* __restrict__ ln1b0,
                                               float* __restrict__ q,
                                               unsigned short* __restrict__ kn,
                                               unsigned short* __restrict__ qn0,
                                               int fold) {
    int rid = blockIdx.x;  // 0..69631
    int buf = rid / 34816;
    int rem = rid % 34816;
    int seq = rem / 17, t = rem % 17;
    int c = seq >> 10, ij = seq & 1023, i = ij >> 5, j = ij & 31;
    const float* src;
    if (buf == 0) {  // q tensor
        if (c == 0)
            src = (t == 0) ? img_cls : img_n + ((size_t)i * 196 + idx_i[ij * 16 + t - 1]) * 512;
        else
            src = (t == 0) ? txt_cls : txt_n + ((size_t)j * 77 + idx_t[ij * 16 + t - 1]) * 512;
    } else {  // k tensor
        if (c == 0)
            src = (t == 0) ? (txt_feat + (size_t)j * 512)
                           : txt_n + ((size_t)j * 77 + idx_t[ij * 16 + t - 1]) * 512;
        else
            src = (t == 0) ? (img_feat + (size_t)i * 512)
                           : img_n + ((size_t)i * 196 + idx_i[ij * 16 + t - 1]) * 512;
    }
    int lane = threadIdx.x;
    const float* sp = src + lane * 8;
    float4 x0 = *(const float4*)sp;
    float4 x1 = *(const float4*)(sp + 4);
    float v[8] = {x0.x, x0.y, x0.z, x0.w, x1.x, x1.y, x1.z, x1.w};
    float s = 0.f, qq = 0.f;
#pragma unroll
    for (int e = 0; e < 8; e++) { s += v[e]; qq += v[e] * v[e]; }
#pragma unroll
    for (int off = 32; off; off >>= 1) {
        s += __shfl_xor(s, off);
        qq += __shfl_xor(qq, off);
    }
    float mean = s * (1.f / 512.f);
    float var = qq * (1.f / 512.f) - mean * mean;
    float rs = rsqrtf(var + 1e-5f);
    size_t row = (size_t)seq * 17 + t;
    if (buf == 0) {
        float* qd = q + row * 512 + lane * 8;
        *(float4*)qd = x0;
        *(float4*)(qd + 4) = x1;
        if (fold) {
            short8 o;
#pragma unroll
            for (int e = 0; e < 8; e++)
                o[e] = (short)f2bf((v[e] - mean) * rs * ln1w0[lane * 8 + e] + ln1b0[lane * 8 + e]);
            *(short8*)(qn0 + row * 512 + lane * 8) = o;
        }
    } else {
        short8 o;
#pragma unroll
        for (int e = 0; e < 8; e++) o[e] = (short)f2bf((v[e] - mean) * rs);
        *(short8*)(kn + row * 512 + lane * 8) = o;
    }
}

// ---------------- LayerNorm: wave-per-row (4 rows/block), shuffle-only -------
__global__ __launch_bounds__(256) void k_ln(const float* __restrict__ xv,
                                            const float* __restrict__ w,
                                            const float* __restrict__ b,
                                            unsigned short* __restrict__ out) {
    int wv = threadIdx.x >> 6, lane = threadIdx.x & 63;
    size_t row = (size_t)blockIdx.x * 4 + wv;
    const float* xr = xv + row * 512 + lane * 8;
    float4 x0 = *(const float4*)xr;
    float4 x1 = *(const float4*)(xr + 4);
    float v[8] = {x0.x, x0.y, x0.z, x0.w, x1.x, x1.y, x1.z, x1.w};
    float s = 0.f, qq = 0.f;
#pragma unroll
    for (int e = 0; e < 8; e++) { s += v[e]; qq += v[e] * v[e]; }
#pragma unroll
    for (int off = 32; off; off >>= 1) {
        s += __shfl_xor(s, off);
        qq += __shfl_xor(qq, off);
    }
    float mean = s * (1.f / 512.f);
    float var = qq * (1.f / 512.f) - mean * mean;
    float rs = rsqrtf(var + 1e-5f);
    const float* wr = w + lane * 8;
    const float* br = b + lane * 8;
    float4 w0 = *(const float4*)wr, w1 = *(const float4*)(wr + 4);
    float4 b0 = *(const float4*)br, b1 = *(const float4*)(br + 4);
    float wv8[8] = {w0.x, w0.y, w0.z, w0.w, w1.x, w1.y, w1.z, w1.w};
    float bv8[8] = {b0.x, b0.y, b0.z, b0.w, b1.x, b1.y, b1.z, b1.w};
    short8 res;
#pragma unroll
    for (int e = 0; e < 8; e++)
        res[e] = (short)f2bf((v[e] - mean) * rs * wv8[e] + bv8[e]);
    *(short8*)(out + row * 512 + lane * 8) = res;
}

// ---------------- round-7/11 GEMM engine + coalesced bf16 epilogue -----------
// C(MxN) = A(MxK) @ W(NxK)^T + bias.  1-D grid, nwg = (M/128)*nxt, nxt = N/128.
// MODE 0: C bf16;  MODE 1: C bf16 = gelu;  MODE 2: C f32 += val.
template <int MODE>
__global__ __launch_bounds__(256) void k_gemm(const unsigned short* __restrict__ A,
                                              const unsigned short* __restrict__ W,
                                              const float* __restrict__ bias,
                                              void* __restrict__ Cv, int K, int ldc, int nxt) {
    __shared__ __align__(16) short sU[2][8192];  // slot: A 4096 | B 4096 shorts

    // bijective XCD swizzle (m204 variant)
    int nwg = gridDim.x;
    int orig = blockIdx.x;
    int q8 = nwg >> 3, r8 = nwg & 7;
    int xcd = orig & 7, base = orig >> 3;
    int swz = (xcd < r8 ? xcd * (q8 + 1) : r8 * (q8 + 1) + (xcd - r8) * q8) + base;
    int tn = swz % nxt, tm = swz / nxt;

    int tid = threadIdx.x;
    int lane = tid & 63;
    int w = tid >> 6;
    int wm = w >> 1, wn = w & 1;
    int r16 = lane & 15, g = lane >> 4;

    int srow = tid >> 2;
    int sgran = tid & 3;
    int gchunk = (sgran ^ ((srow ^ (srow >> 2)) & 3)) * 8;  // elems
    const short* gA = (const short*)A + ((size_t)tm * 128 + srow) * K + gchunk;
    const short* gB = (const short*)W + ((size_t)tn * 128 + srow) * K + gchunk;
    int ldst = tid * 8;

    f32x4 acc[4][4] = {};
    int NU = K >> 5;

#define STAGE_UNIT(U, S)                                              \
    do {                                                              \
        size_t ko_ = (size_t)(U) * 32;                                \
        gload16(gA + ko_, &sU[(S)][ldst]);                            \
        gload16(gA + (size_t)64 * K + ko_, &sU[(S)][2048 + ldst]);    \
        gload16(gB + ko_, &sU[(S)][4096 + ldst]);                     \
        gload16(gB + (size_t)64 * K + ko_, &sU[(S)][6144 + ldst]);    \
    } while (0)

    STAGE_UNIT(0, 0);
    STAGE_UNIT(1, 1);

    int s = 0;
    for (int u = 0; u < NU; ++u) {
        if (u + 1 < NU) asm volatile("s_waitcnt vmcnt(4)" ::: "memory");
        else            asm volatile("s_waitcnt vmcnt(0)" ::: "memory");
        __builtin_amdgcn_s_barrier();
        __builtin_amdgcn_sched_barrier(0);

        const short* SA = &sU[s][0];
        const short* SB = &sU[s][4096];
        short8 a[4], b[4];
#pragma unroll
        for (int m = 0; m < 4; m++) {
            int row = wm * 64 + m * 16 + r16;
            a[m] = *(const short8*)&SA[row * 32 + ((g ^ ((row ^ (row >> 2)) & 3)) << 3)];
        }
#pragma unroll
        for (int n = 0; n < 4; n++) {
            int row = wn * 64 + n * 16 + r16;
            b[n] = *(const short8*)&SB[row * 32 + ((g ^ ((row ^ (row >> 2)) & 3)) << 3)];
        }
        __builtin_amdgcn_s_setprio(1);
#pragma unroll
        for (int m = 0; m < 4; m++)
#pragma unroll
            for (int n = 0; n < 4; n++)
                acc[m][n] = __builtin_amdgcn_mfma_f32_16x16x32_bf16(a[m], b[n], acc[m][n], 0, 0, 0);
        __builtin_amdgcn_s_setprio(0);
        __builtin_amdgcn_sched_barrier(0);
        __builtin_amdgcn_s_barrier();
        if (u + 2 < NU) STAGE_UNIT(u + 2, s);
        s ^= 1;
    }
#undef STAGE_UNIT

    if (MODE == 2) {
        size_t rbase = (size_t)tm * 128 + wm * 64 + g * 4;
        size_t cbase = (size_t)tn * 128 + wn * 64 + r16;
#pragma unroll
        for (int m = 0; m < 4; m++)
#pragma unroll
            for (int n = 0; n < 4; n++) {
                size_t col = cbase + n * 16;
                float bv = bias ? bias[col] : 0.f;
#pragma unroll
                for (int r = 0; r < 4; r++) {
                    size_t row = rbase + m * 16 + r;
                    ((float*)Cv)[row * ldc + col] += acc[m][n][r] + bv;
                }
            }
    } else {
        short* sC = &sU[0][0];
        int lrow = wm * 64 + g * 4;
        int lcol = wn * 64 + r16;
#pragma unroll
        for (int n = 0; n < 4; n++) {
            float bv = bias ? bias[(size_t)tn * 128 + lcol + n * 16] : 0.f;
#pragma unroll
            for (int m = 0; m < 4; m++)
#pragma unroll
                for (int r = 0; r < 4; r++) {
                    float val = acc[m][n][r] + bv;
                    if (MODE == 1) val = val / (1.f + __expf(-1.702f * val));
                    sC[(lrow + m * 16 + r) * 128 + lcol + n * 16] = (short)f2bf(val);
                }
        }
        __builtin_amdgcn_s_barrier();
        unsigned short* C = (unsigned short*)Cv;
#pragma unroll
        for (int p = 0; p < 8; p++) {
            int idx = p * 256 + tid;
            int row = idx >> 4;
            int cc = idx & 15;
            *(short8*)(C + ((size_t)tm * 128 + row) * ldc + (size_t)tn * 128 + cc * 8) =
                *(const short8*)&sC[row * 128 + cc * 8];
        }
    }
}

// ---------------- attention: per-seq block (512 thr = 8 waves = 8 heads) ------
__global__ __launch_bounds__(512) void k_attn(const unsigned short* __restrict__ Qm,
                                              const unsigned short* __restrict__ KVm,
                                              unsigned short* __restrict__ Om) {
    __shared__ __align__(16) short sAll[3 * 17 * 520];
    __shared__ float sP[8 * 17 * 17];
    int seq = blockIdx.x;
    size_t tb = (size_t)seq * 17;
    for (int c = threadIdx.x; c < 3264; c += 512) {
        int mat = c / 1088, rem = c % 1088, row = rem >> 6, ch = rem & 63;
        const short8* src;
        if (mat == 0)
            src = (const short8*)(Qm + (tb + row) * 512 + ch * 8);
        else if (mat == 1)
            src = (const short8*)(KVm + (tb + row) * 1024 + ch * 8);
        else
            src = (const short8*)(KVm + (tb + row) * 1024 + 512 + ch * 8);
        *(short8*)&sAll[mat * (17 * 520) + row * 520 + ch * 8] = *src;
    }
    __syncthreads();
    int h = threadIdx.x >> 6, lane = threadIdx.x & 63;
    const short* sQ = sAll;
    const short* sK = sAll + 17 * 520;
    const short* sV = sAll + 2 * 17 * 520;
    int jj = lane < 17 ? lane : 0;
    for (int i = 0; i < 17; i++) {
        float acc = 0.f;
#pragma unroll
        for (int c = 0; c < 8; c++) {
            short8 q8 = *(const short8*)&sQ[i * 520 + h * 64 + c * 8];
            short8 k8 = *(const short8*)&sK[jj * 520 + h * 64 + c * 8];
#pragma unroll
            for (int e = 0; e < 8; e++) acc += bf2f(q8[e]) * bf2f(k8[e]);
        }
        float sc = (lane < 17) ? acc * 0.125f : -1e30f;
        float m = sc;
#pragma unroll
        for (int off = 32; off; off >>= 1) m = fmaxf(m, __shfl_xor(m, off));
        float p = (lane < 17) ? __expf(sc - m) : 0.f;
        float sum = p;
#pragma unroll
        for (int off = 32; off; off >>= 1) sum += __shfl_xor(sum, off);
        if (lane < 17) sP[(h * 17 + i) * 17 + lane] = p / sum;
    }
    for (int i = 0; i < 17; i++) {
        float o = 0.f;
#pragma unroll
        for (int t = 0; t < 17; t++)
            o += sP[(h * 17 + i) * 17 + t] * bf2f(sV[t * 520 + h * 64 + lane]);
        Om[(tb + i) * 512 + h * 64 + lane] = f2bf(o);
    }
}

// ---------------------------------------------------------------------------
extern "C" void kernel_launch(void* const* d_in, const int* in_sizes, int n_in,
                              void* d_out, int out_size, void* d_ws, size_t ws_size,
                              hipStream_t stream) {
    const float* image_feature = (const float*)d_in[0];
    const float* image_tokens = (const float*)d_in[1];
    const float* text_feature = (const float*)d_in[2];
    const float* text_tokens = (const float*)d_in[3];
    const int* atte_mask = (const int*)d_in[4];
    const float* img_cls = (const float*)d_in[5];
    const float* txt_cls = (const float*)d_in[6];
    const float* in_proj_w = (const float*)d_in[7];
    const float* in_proj_b = (const float*)d_in[8];
    const float* out_w = (const float*)d_in[9];
    const float* out_b = (const float*)d_in[10];
    const float* ln1_w = (const float*)d_in[11];
    const float* ln1_b = (const float*)d_in[12];
    const float* ln2_w = (const float*)d_in[13];
    const float* ln2_b = (const float*)d_in[14];
    const float* ln3_w = (const float*)d_in[15];
    const float* ln3_b = (const float*)d_in[16];
    const float* fc_w = (const float*)d_in[17];
    const float* fc_b = (const float*)d_in[18];
    const float* proj_w = (const float*)d_in[19];
    const float* proj_b = (const float*)d_in[20];

    // ---- workspace layout (adaptive) ----
    char* ws = (char*)d_ws;
    const size_t OFF_K = 12582912;               // kn (normalized) bf16
    const size_t OFF_B2 = OFF_K + 35651584;      // b2eff 8KB
    const size_t OFF_CH = OFF_B2 + 8192;         // chunk region
    size_t avail = ws_size > OFF_CH ? ws_size - OFF_CH : 0;
    int C = 2048;  // seqs per chunk
    while (C > 256 && (size_t)87040 * C > avail) C >>= 1;
    int nch = 2048 / C;

    unsigned short* wbf = (unsigned short*)ws;
    unsigned short* w_inproj = wbf;                // 2*1536*512 elems
    unsigned short* w_outp = wbf + 1572864;        // 2*512*512
    unsigned short* w_fc = wbf + 2097152;          // 2*2048*512
    unsigned short* w_proj = wbf + 4194304;        // 2*512*2048
    unsigned short* kstream = (unsigned short*)(ws + OFF_K);
    float* b2eff = (float*)(ws + OFF_B2);
    char* chreg = ws + OFF_CH;
    // early overlay
    float* img_n = (float*)(chreg + 0);            // 12,845,056
    float* txt_n = (float*)(chreg + 12845056);     //  5,046,272
    float* isum = (float*)(chreg + 17891328);      //     65,536
    float* tmask = (float*)(chreg + 17956864);     //     65,536
    float* simg = (float*)(chreg + 18022400);      //    802,816
    float* stxt = (float*)(chreg + 18825216);      //    315,392
    int* idx_i = (int*)(chreg + 19140608);         //     65,536
    int* idx_t = (int*)(chreg + 19206144);         //     65,536
    // chunk-time pointers
    unsigned short* qn = (unsigned short*)chreg;                      // 17408*C B
    unsigned short* qkvQ = (unsigned short*)(chreg + (size_t)17408 * C);
    unsigned short* qkvKV = (unsigned short*)(chreg + (size_t)34816 * C);
    unsigned short* atto = (unsigned short*)(chreg + (size_t)69632 * C);
    unsigned short* hbuf = qkvQ;  // 69632*C B, overlays qkvQ+qkvKV+atto
    unsigned short* qn0 = atto;   // layer-0 folded LN1 output (nch==1 only)
    float* q = (float*)d_out;
    int fold = (nch == 1) ? 1 : 0;

    // weights -> bf16 (Wkv columns scaled by ln2_w); effective kv bias
    k_f2b4<<<3072, 256, 0, stream>>>(in_proj_w, out_w, fc_w, proj_w, ln2_w, wbf);
    k_bias2<<<512, 256, 0, stream>>>(in_proj_w, in_proj_b, ln2_b, b2eff);

    // token normalize
    k_l2norm<<<6272, 256, 0, stream>>>(image_tokens, img_n);
    k_l2norm<<<2464, 256, 0, stream>>>(text_tokens, txt_n);

    // factored score vectors
    k_colsum<<<32, 512, 0, stream>>>(img_n, nullptr, isum, 196);
    k_colsum<<<32, 512, 0, stream>>>(txt_n, atte_mask, tmask, 77);

    // scores (token rows read once; bitwise-identical values) + top-k + gather
    k_scores<<<256, 256, 0, stream>>>(img_n, tmask, simg, 196, 25, 0);
    k_scores<<<256, 256, 0, stream>>>(txt_n, isum, stxt, 77, 10, 1);
    k_topk<<<2048, 64, 0, stream>>>(simg, stxt, idx_i, idx_t);
    k_gather<<<69632, 64, 0, stream>>>(img_n, txt_n, image_feature, text_feature,
                                       img_cls, txt_cls, idx_i, idx_t,
                                       ln1_w, ln1_b, q, kstream, qn0, fold);

    // 2-layer cross-attention transformer, chunked over sequences
    for (int ch = 0; ch < nch; ch++) {
        size_t r0 = (size_t)ch * C * 17;
        float* qc = q + r0 * 512;
        const unsigned short* kc = kstream + r0 * 512;
        int rowsC = 17 * C;
        int gmt = rowsC / 128;  // M-tiles
        int gln = rowsC / 4;    // LN blocks (4 rows each)
        for (int l = 0; l < 2; l++) {
            const unsigned short* Wq = w_inproj + (size_t)l * 786432;
            const unsigned short* Wkv = Wq + 262144;
            const float* bq = in_proj_b + l * 1536;
            const unsigned short* Aq;
            if (l == 0 && fold) {
                Aq = qn0;  // gather wrote LN1_0 output
            } else {
                k_ln<<<gln, 256, 0, stream>>>(qc, ln1_w + l * 512, ln1_b + l * 512, qn);
                Aq = qn;
            }
            k_gemm<0><<<gmt * 4, 256, 0, stream>>>(Aq, Wq, bq, qkvQ, 512, 512, 4);
            k_gemm<0><<<gmt * 8, 256, 0, stream>>>(kc, Wkv, b2eff + l * 1024, qkvKV,
                                                   512, 1024, 8);
            k_attn<<<C, 512, 0, stream>>>(qkvQ, qkvKV, atto);
            k_gemm<2><<<gmt * 4, 256, 0, stream>>>(atto, w_outp + (size_t)l * 262144,
                                                   out_b + l * 512, qc, 512, 512, 4);
            k_ln<<<gln, 256, 0, stream>>>(qc, ln3_w + l * 512, ln3_b + l * 512, qn);
            k_gemm<1><<<gmt * 16, 256, 0, stream>>>(qn, w_fc + (size_t)l * 1048576,
                                                    fc_b + l * 2048, hbuf, 512, 2048, 16);
            k_gemm<2><<<gmt * 4, 256, 0, stream>>>(hbuf, w_proj + (size_t)l * 1048576,
                                                   proj_b + l * 512, qc, 2048, 512, 4);
        }
    }
}

// Round 14
// 1166.600 us; speedup vs baseline: 1.1138x; 1.1138x over previous
//
#include <hip/hip_runtime.h>
#include <hip/hip_bf16.h>
#include <stdint.h>

// ---------------------------------------------------------------------------
// Alignment_49735721287759: CLIP-style alignment head on MI355X (gfx950)
// Round 14 = round-12 (best, 1238us; k_scores REVERTED from round-13's
// L3-blind rewrite) + wave-paired attention QK/softmax (2 query rows per
// iteration, 9 instead of 17 passes; reduction trees bitwise-identical).
// GEMM engine / LN folding / gather unchanged from round 12.
// ---------------------------------------------------------------------------

typedef __attribute__((ext_vector_type(8))) short short8;
typedef __attribute__((ext_vector_type(4))) float f32x4;

__device__ __forceinline__ float bf2f(short u) {
    return __uint_as_float(((uint32_t)(uint16_t)u) << 16);
}
__device__ __forceinline__ unsigned short f2bf(float f) {
    __hip_bfloat16 h = __float2bfloat16(f);
    return *reinterpret_cast<unsigned short*>(&h);
}
__device__ __forceinline__ void gload16(const void* g, void* l) {
    __builtin_amdgcn_global_load_lds(
        (const __attribute__((address_space(1))) unsigned int*)g,
        (__attribute__((address_space(3))) unsigned int*)l, 16, 0, 0);
}

// ---------------- fused f32 -> bf16 convert; Wkv columns scaled by ln2_w -----
__global__ __launch_bounds__(256) void k_f2b4(const float* __restrict__ s0,
                                              const float* __restrict__ s1,
                                              const float* __restrict__ s2,
                                              const float* __restrict__ s3,
                                              const float* __restrict__ ln2w,
                                              unsigned short* __restrict__ out) {
    for (int i = blockIdx.x * 256 + threadIdx.x; i < 6291456; i += gridDim.x * 256) {
        float v;
        if (i < 1572864) {
            v = s0[i];
            int rem = i % 786432;            // within layer: r*512+c
            if (rem >= 262144) {             // rows 512..1535 = K,V
                int l = i / 786432;
                v *= ln2w[l * 512 + (i & 511)];
            }
        } else if (i < 2097152) v = s1[i - 1572864];
        else if (i < 4194304) v = s2[i - 2097152];
        else v = s3[i - 4194304];
        out[i] = f2bf(v);
    }
}

// ---------------- effective kv bias: b2eff[l][n] = ln2_b_l . Wkv_l[n,:] + bkv
__global__ __launch_bounds__(256) void k_bias2(const float* __restrict__ in_proj_w,
                                               const float* __restrict__ in_proj_b,
                                               const float* __restrict__ ln2_b,
                                               float* __restrict__ b2eff) {
    int gid = blockIdx.x * 4 + (threadIdx.x >> 6);  // 0..2047
    int l = gid >> 10, o = gid & 1023;
    int lane = threadIdx.x & 63;
    const float* wr = in_proj_w + ((size_t)l * 1536 + 512 + o) * 512 + lane * 8;
    const float* b2 = ln2_b + l * 512 + lane * 8;
    float acc = 0.f;
#pragma unroll
    for (int e = 0; e < 8; e++) acc += wr[e] * b2[e];
#pragma unroll
    for (int off = 32; off; off >>= 1) acc += __shfl_xor(acc, off);
    if (lane == 0) b2eff[l * 1024 + o] = acc + in_proj_b[l * 1536 + 512 + o];
}

// ---------------- row L2 normalize (512-wide rows) ----------------
__global__ __launch_bounds__(256) void k_l2norm(const float* __restrict__ in,
                                                float* __restrict__ out) {
    size_t row = blockIdx.x;
    const float* x = in + row * 512;
    int t = threadIdx.x;
    float a0 = x[t], a1 = x[t + 256];
    float ss = a0 * a0 + a1 * a1;
#pragma unroll
    for (int off = 32; off; off >>= 1) ss += __shfl_xor(ss, off);
    __shared__ float s4[4];
    if ((t & 63) == 0) s4[t >> 6] = ss;
    __syncthreads();
    float tot = s4[0] + s4[1] + s4[2] + s4[3];
    float inv = 1.0f / sqrtf(tot);
    out[row * 512 + t] = a0 * inv;
    out[row * 512 + t + 256] = a1 * inv;
}

// ---------------- column sum over tokens (optionally masked) ----------------
__global__ __launch_bounds__(512) void k_colsum(const float* __restrict__ tok,
                                                const int* __restrict__ mask,
                                                float* __restrict__ out, int R) {
    int b = blockIdx.x;
    int d = threadIdx.x;  // 512 threads
    float acc = 0.f;
    for (int r = 0; r < R; r++) {
        float m = mask ? (float)mask[b * R + r] : 1.f;
        acc += m * tok[((size_t)b * R + r) * 512 + d];
    }
    out[b * 512 + d] = acc;
}

// ---------------- factored scores (round-12 form; L2/L3 serve re-reads) ------
__global__ __launch_bounds__(256) void k_scores(const float* __restrict__ tok,
                                                const float* __restrict__ vec,
                                                float* __restrict__ out, int R, int swap) {
    int bid = blockIdx.x;
    int i = bid >> 5, j = bid & 31;
    int tb = swap ? j : i;
    int vb = swap ? i : j;
    __shared__ float sv[512];
    for (int t = threadIdx.x; t < 512; t += 256) sv[t] = vec[vb * 512 + t];
    __syncthreads();
    int wv = threadIdx.x >> 6, lane = threadIdx.x & 63;
    for (int r = wv; r < R; r += 4) {
        const float* tr = tok + ((size_t)tb * R + r) * 512;
        float acc = 0.f;
#pragma unroll
        for (int c = 0; c < 8; c++) {
            int d = lane + c * 64;
            acc += tr[d] * sv[d];
        }
#pragma unroll
        for (int off = 32; off; off >>= 1) acc += __shfl_xor(acc, off);
        if (lane == 0) out[(size_t)bid * R + r] = acc;
    }
}

// ---------------- top-16 (values desc, ties -> lowest idx), output sorted asc
__global__ __launch_bounds__(64) void k_topk(const float* __restrict__ simg,
                                             const float* __restrict__ stxt,
                                             int* __restrict__ idx_i, int* __restrict__ idx_t) {
    int bid = blockIdx.x;  // 0..2047: first 1024 img (n=196), then txt (n=77)
    bool isimg = bid < 1024;
    int ij = isimg ? bid : bid - 1024;
    const float* s = isimg ? simg + (size_t)ij * 196 : stxt + (size_t)ij * 77;
    int n = isimg ? 196 : 77;
    int* out = (isimg ? idx_i : idx_t) + ij * 16;
    int lane = threadIdx.x;
    float v[4];
    int ids[4];
#pragma unroll
    for (int k = 0; k < 4; k++) {
        int id = lane + k * 64;
        ids[k] = id;
        v[k] = (id < n) ? s[id] : -3.0e38f;
    }
    __shared__ int sel[16];
    for (int r = 0; r < 16; r++) {
        float bv = v[0];
        int bi = ids[0];
#pragma unroll
        for (int k = 1; k < 4; k++)
            if (v[k] > bv) { bv = v[k]; bi = ids[k]; }
#pragma unroll
        for (int off = 32; off; off >>= 1) {
            float ov = __shfl_xor(bv, off);
            int oi = __shfl_xor(bi, off);
            if (ov > bv || (ov == bv && oi < bi)) { bv = ov; bi = oi; }
        }
        if (lane == 0) sel[r] = bi;
#pragma unroll
        for (int k = 0; k < 4; k++)
            if (ids[k] == bi) v[k] = -3.0e38f;
    }
    if (lane == 0) {
        for (int a = 1; a < 16; a++) {
            int key = sel[a];
            int b = a - 1;
            while (b >= 0 && sel[b] > key) { sel[b + 1] = sel[b]; b--; }
            sel[b + 1] = key;
        }
        for (int a = 0; a < 16; a++) out[a] = sel[a];
    }
}

// ---------------- gather + fused row-stats normalization ---------------------
__global__ __launch_bounds__(64) void k_gather(const float* __restrict__ img_n,
                                               const float* __restrict__ txt_n,
                                               const float* __restrict__ img_feat,
                                               const float* __restrict__ txt_feat,
                                               const float* __restrict__ img_cls,
                                               const float* __restrict__ txt_cls,
                                               const int* __restrict__ idx_i,
                                               const int* __restrict__ idx_t,
                                               const float* __restrict__ ln1w0,
                                               const float* __restrict__ ln1b0,
                                               float* __restrict__ q,
                                               unsigned short* __restrict__ kn,
                                               unsigned short* __restrict__ qn0,
                                               int fold) {
    int rid = blockIdx.x;  // 0..69631
    int buf = rid / 34816;
    int rem = rid % 34816;
    int seq = rem / 17, t = rem % 17;
    int c = seq >> 10, ij = seq & 1023, i = ij >> 5, j = ij & 31;
    const float* src;
    if (buf == 0) {  // q tensor
        if (c == 0)
            src = (t == 0) ? img_cls : img_n + ((size_t)i * 196 + idx_i[ij * 16 + t - 1]) * 512;
        else
            src = (t == 0) ? txt_cls : txt_n + ((size_t)j * 77 + idx_t[ij * 16 + t - 1]) * 512;
    } else {  // k tensor
        if (c == 0)
            src = (t == 0) ? (txt_feat + (size_t)j * 512)
                           : txt_n + ((size_t)j * 77 + idx_t[ij * 16 + t - 1]) * 512;
        else
            src = (t == 0) ? (img_feat + (size_t)i * 512)
                           : img_n + ((size_t)i * 196 + idx_i[ij * 16 + t - 1]) * 512;
    }
    int lane = threadIdx.x;
    const float* sp = src + lane * 8;
    float4 x0 = *(const float4*)sp;
    float4 x1 = *(const float4*)(sp + 4);
    float v[8] = {x0.x, x0.y, x0.z, x0.w, x1.x, x1.y, x1.z, x1.w};
    float s = 0.f, qq = 0.f;
#pragma unroll
    for (int e = 0; e < 8; e++) { s += v[e]; qq += v[e] * v[e]; }
#pragma unroll
    for (int off = 32; off; off >>= 1) {
        s += __shfl_xor(s, off);
        qq += __shfl_xor(qq, off);
    }
    float mean = s * (1.f / 512.f);
    float var = qq * (1.f / 512.f) - mean * mean;
    float rs = rsqrtf(var + 1e-5f);
    size_t row = (size_t)seq * 17 + t;
    if (buf == 0) {
        float* qd = q + row * 512 + lane * 8;
        *(float4*)qd = x0;
        *(float4*)(qd + 4) = x1;
        if (fold) {
            short8 o;
#pragma unroll
            for (int e = 0; e < 8; e++)
                o[e] = (short)f2bf((v[e] - mean) * rs * ln1w0[lane * 8 + e] + ln1b0[lane * 8 + e]);
            *(short8*)(qn0 + row * 512 + lane * 8) = o;
        }
    } else {
        short8 o;
#pragma unroll
        for (int e = 0; e < 8; e++) o[e] = (short)f2bf((v[e] - mean) * rs);
        *(short8*)(kn + row * 512 + lane * 8) = o;
    }
}

// ---------------- LayerNorm: wave-per-row (4 rows/block), shuffle-only -------
__global__ __launch_bounds__(256) void k_ln(const float* __restrict__ xv,
                                            const float* __restrict__ w,
                                            const float* __restrict__ b,
                                            unsigned short* __restrict__ out) {
    int wv = threadIdx.x >> 6, lane = threadIdx.x & 63;
    size_t row = (size_t)blockIdx.x * 4 + wv;
    const float* xr = xv + row * 512 + lane * 8;
    float4 x0 = *(const float4*)xr;
    float4 x1 = *(const float4*)(xr + 4);
    float v[8] = {x0.x, x0.y, x0.z, x0.w, x1.x, x1.y, x1.z, x1.w};
    float s = 0.f, qq = 0.f;
#pragma unroll
    for (int e = 0; e < 8; e++) { s += v[e]; qq += v[e] * v[e]; }
#pragma unroll
    for (int off = 32; off; off >>= 1) {
        s += __shfl_xor(s, off);
        qq += __shfl_xor(qq, off);
    }
    float mean = s * (1.f / 512.f);
    float var = qq * (1.f / 512.f) - mean * mean;
    float rs = rsqrtf(var + 1e-5f);
    const float* wr = w + lane * 8;
    const float* br = b + lane * 8;
    float4 w0 = *(const float4*)wr, w1 = *(const float4*)(wr + 4);
    float4 b0 = *(const float4*)br, b1 = *(const float4*)(br + 4);
    float wv8[8] = {w0.x, w0.y, w0.z, w0.w, w1.x, w1.y, w1.z, w1.w};
    float bv8[8] = {b0.x, b0.y, b0.z, b0.w, b1.x, b1.y, b1.z, b1.w};
    short8 res;
#pragma unroll
    for (int e = 0; e < 8; e++)
        res[e] = (short)f2bf((v[e] - mean) * rs * wv8[e] + bv8[e]);
    *(short8*)(out + row * 512 + lane * 8) = res;
}

// ---------------- round-7/11 GEMM engine + coalesced bf16 epilogue -----------
// C(MxN) = A(MxK) @ W(NxK)^T + bias.  1-D grid, nwg = (M/128)*nxt, nxt = N/128.
// MODE 0: C bf16;  MODE 1: C bf16 = gelu;  MODE 2: C f32 += val.
template <int MODE>
__global__ __launch_bounds__(256) void k_gemm(const unsigned short* __restrict__ A,
                                              const unsigned short* __restrict__ W,
                                              const float* __restrict__ bias,
                                              void* __restrict__ Cv, int K, int ldc, int nxt) {
    __shared__ __align__(16) short sU[2][8192];  // slot: A 4096 | B 4096 shorts

    // bijective XCD swizzle (m204 variant)
    int nwg = gridDim.x;
    int orig = blockIdx.x;
    int q8 = nwg >> 3, r8 = nwg & 7;
    int xcd = orig & 7, base = orig >> 3;
    int swz = (xcd < r8 ? xcd * (q8 + 1) : r8 * (q8 + 1) + (xcd - r8) * q8) + base;
    int tn = swz % nxt, tm = swz / nxt;

    int tid = threadIdx.x;
    int lane = tid & 63;
    int w = tid >> 6;
    int wm = w >> 1, wn = w & 1;
    int r16 = lane & 15, g = lane >> 4;

    int srow = tid >> 2;
    int sgran = tid & 3;
    int gchunk = (sgran ^ ((srow ^ (srow >> 2)) & 3)) * 8;  // elems
    const short* gA = (const short*)A + ((size_t)tm * 128 + srow) * K + gchunk;
    const short* gB = (const short*)W + ((size_t)tn * 128 + srow) * K + gchunk;
    int ldst = tid * 8;

    f32x4 acc[4][4] = {};
    int NU = K >> 5;

#define STAGE_UNIT(U, S)                                              \
    do {                                                              \
        size_t ko_ = (size_t)(U) * 32;                                \
        gload16(gA + ko_, &sU[(S)][ldst]);                            \
        gload16(gA + (size_t)64 * K + ko_, &sU[(S)][2048 + ldst]);    \
        gload16(gB + ko_, &sU[(S)][4096 + ldst]);                     \
        gload16(gB + (size_t)64 * K + ko_, &sU[(S)][6144 + ldst]);    \
    } while (0)

    STAGE_UNIT(0, 0);
    STAGE_UNIT(1, 1);

    int s = 0;
    for (int u = 0; u < NU; ++u) {
        if (u + 1 < NU) asm volatile("s_waitcnt vmcnt(4)" ::: "memory");
        else            asm volatile("s_waitcnt vmcnt(0)" ::: "memory");
        __builtin_amdgcn_s_barrier();
        __builtin_amdgcn_sched_barrier(0);

        const short* SA = &sU[s][0];
        const short* SB = &sU[s][4096];
        short8 a[4], b[4];
#pragma unroll
        for (int m = 0; m < 4; m++) {
            int row = wm * 64 + m * 16 + r16;
            a[m] = *(const short8*)&SA[row * 32 + ((g ^ ((row ^ (row >> 2)) & 3)) << 3)];
        }
#pragma unroll
        for (int n = 0; n < 4; n++) {
            int row = wn * 64 + n * 16 + r16;
            b[n] = *(const short8*)&SB[row * 32 + ((g ^ ((row ^ (row >> 2)) & 3)) << 3)];
        }
        __builtin_amdgcn_s_setprio(1);
#pragma unroll
        for (int m = 0; m < 4; m++)
#pragma unroll
            for (int n = 0; n < 4; n++)
                acc[m][n] = __builtin_amdgcn_mfma_f32_16x16x32_bf16(a[m], b[n], acc[m][n], 0, 0, 0);
        __builtin_amdgcn_s_setprio(0);
        __builtin_amdgcn_sched_barrier(0);
        __builtin_amdgcn_s_barrier();
        if (u + 2 < NU) STAGE_UNIT(u + 2, s);
        s ^= 1;
    }
#undef STAGE_UNIT

    if (MODE == 2) {
        size_t rbase = (size_t)tm * 128 + wm * 64 + g * 4;
        size_t cbase = (size_t)tn * 128 + wn * 64 + r16;
#pragma unroll
        for (int m = 0; m < 4; m++)
#pragma unroll
            for (int n = 0; n < 4; n++) {
                size_t col = cbase + n * 16;
                float bv = bias ? bias[col] : 0.f;
#pragma unroll
                for (int r = 0; r < 4; r++) {
                    size_t row = rbase + m * 16 + r;
                    ((float*)Cv)[row * ldc + col] += acc[m][n][r] + bv;
                }
            }
    } else {
        short* sC = &sU[0][0];
        int lrow = wm * 64 + g * 4;
        int lcol = wn * 64 + r16;
#pragma unroll
        for (int n = 0; n < 4; n++) {
            float bv = bias ? bias[(size_t)tn * 128 + lcol + n * 16] : 0.f;
#pragma unroll
            for (int m = 0; m < 4; m++)
#pragma unroll
                for (int r = 0; r < 4; r++) {
                    float val = acc[m][n][r] + bv;
                    if (MODE == 1) val = val / (1.f + __expf(-1.702f * val));
                    sC[(lrow + m * 16 + r) * 128 + lcol + n * 16] = (short)f2bf(val);
                }
        }
        __builtin_amdgcn_s_barrier();
        unsigned short* C = (unsigned short*)Cv;
#pragma unroll
        for (int p = 0; p < 8; p++) {
            int idx = p * 256 + tid;
            int row = idx >> 4;
            int cc = idx & 15;
            *(short8*)(C + ((size_t)tm * 128 + row) * ldc + (size_t)tn * 128 + cc * 8) =
                *(const short8*)&sC[row * 128 + cc * 8];
        }
    }
}

// ---------------- attention: per-seq block (512 thr = 8 waves = 8 heads) ------
// QK/softmax: 2 query rows per iteration (lanes 0-16 -> row i0, lanes 32-48 ->
// row i0+1); reduce trees (off 16..1 within each half) are bitwise-identical
// to the old 64-wide tree (off=32 step only folded padding identities).
__global__ __launch_bounds__(512) void k_attn(const unsigned short* __restrict__ Qm,
                                              const unsigned short* __restrict__ KVm,
                                              unsigned short* __restrict__ Om) {
    __shared__ __align__(16) short sAll[3 * 17 * 520];
    __shared__ float sP[8 * 17 * 17];
    int seq = blockIdx.x;
    size_t tb = (size_t)seq * 17;
    for (int c = threadIdx.x; c < 3264; c += 512) {
        int mat = c / 1088, rem = c % 1088, row = rem >> 6, ch = rem & 63;
        const short8* src;
        if (mat == 0)
            src = (const short8*)(Qm + (tb + row) * 512 + ch * 8);
        else if (mat == 1)
            src = (const short8*)(KVm + (tb + row) * 1024 + ch * 8);
        else
            src = (const short8*)(KVm + (tb + row) * 1024 + 512 + ch * 8);
        *(short8*)&sAll[mat * (17 * 520) + row * 520 + ch * 8] = *src;
    }
    __syncthreads();
    int h = threadIdx.x >> 6, lane = threadIdx.x & 63;
    const short* sQ = sAll;
    const short* sK = sAll + 17 * 520;
    const short* sV = sAll + 2 * 17 * 520;
    int half = lane >> 5;          // 0: row i0, 1: row i0+1
    int jj = lane & 31;            // key index within half
    int jc = jj < 17 ? jj : 0;     // clamped for safe addressing
    for (int i0 = 0; i0 < 17; i0 += 2) {
        int irow = i0 + half;
        int ic = irow < 17 ? irow : 16;
        float acc = 0.f;
#pragma unroll
        for (int c = 0; c < 8; c++) {
            short8 q8 = *(const short8*)&sQ[ic * 520 + h * 64 + c * 8];
            short8 k8 = *(const short8*)&sK[jc * 520 + h * 64 + c * 8];
#pragma unroll
            for (int e = 0; e < 8; e++) acc += bf2f(q8[e]) * bf2f(k8[e]);
        }
        bool act = (jj < 17) && (irow < 17);
        float sc = act ? acc * 0.125f : -1e30f;
        float m = sc;
#pragma unroll
        for (int off = 16; off; off >>= 1) m = fmaxf(m, __shfl_xor(m, off));
        float p = act ? __expf(sc - m) : 0.f;
        float sum = p;
#pragma unroll
        for (int off = 16; off; off >>= 1) sum += __shfl_xor(sum, off);
        if (act) sP[(h * 17 + irow) * 17 + jj] = p / sum;
    }
    __builtin_amdgcn_s_barrier();
    for (int i = 0; i < 17; i++) {
        float o = 0.f;
#pragma unroll
        for (int t = 0; t < 17; t++)
            o += sP[(h * 17 + i) * 17 + t] * bf2f(sV[t * 520 + h * 64 + lane]);
        Om[(tb + i) * 512 + h * 64 + lane] = f2bf(o);
    }
}

// ---------------------------------------------------------------------------
extern "C" void kernel_launch(void* const* d_in, const int* in_sizes, int n_in,
                              void* d_out, int out_size, void* d_ws, size_t ws_size,
                              hipStream_t stream) {
    const float* image_feature = (const float*)d_in[0];
    const float* image_tokens = (const float*)d_in[1];
    const float* text_feature = (const float*)d_in[2];
    const float* text_tokens = (const float*)d_in[3];
    const int* atte_mask = (const int*)d_in[4];
    const float* img_cls = (const float*)d_in[5];
    const float* txt_cls = (const float*)d_in[6];
    const float* in_proj_w = (const float*)d_in[7];
    const float* in_proj_b = (const float*)d_in[8];
    const float* out_w = (const float*)d_in[9];
    const float* out_b = (const float*)d_in[10];
    const float* ln1_w = (const float*)d_in[11];
    const float* ln1_b = (const float*)d_in[12];
    const float* ln2_w = (const float*)d_in[13];
    const float* ln2_b = (const float*)d_in[14];
    const float* ln3_w = (const float*)d_in[15];
    const float* ln3_b = (const float*)d_in[16];
    const float* fc_w = (const float*)d_in[17];
    const float* fc_b = (const float*)d_in[18];
    const float* proj_w = (const float*)d_in[19];
    const float* proj_b = (const float*)d_in[20];

    // ---- workspace layout (adaptive) ----
    char* ws = (char*)d_ws;
    const size_t OFF_K = 12582912;               // kn (normalized) bf16
    const size_t OFF_B2 = OFF_K + 35651584;      // b2eff 8KB
    const size_t OFF_CH = OFF_B2 + 8192;         // chunk region
    size_t avail = ws_size > OFF_CH ? ws_size - OFF_CH : 0;
    int C = 2048;  // seqs per chunk
    while (C > 256 && (size_t)87040 * C > avail) C >>= 1;
    int nch = 2048 / C;

    unsigned short* wbf = (unsigned short*)ws;
    unsigned short* w_inproj = wbf;                // 2*1536*512 elems
    unsigned short* w_outp = wbf + 1572864;        // 2*512*512
    unsigned short* w_fc = wbf + 2097152;          // 2*2048*512
    unsigned short* w_proj = wbf + 4194304;        // 2*512*2048
    unsigned short* kstream = (unsigned short*)(ws + OFF_K);
    float* b2eff = (float*)(ws + OFF_B2);
    char* chreg = ws + OFF_CH;
    // early overlay
    float* img_n = (float*)(chreg + 0);            // 12,845,056
    float* txt_n = (float*)(chreg + 12845056);     //  5,046,272
    float* isum = (float*)(chreg + 17891328);      //     65,536
    float* tmask = (float*)(chreg + 17956864);     //     65,536
    float* simg = (float*)(chreg + 18022400);      //    802,816
    float* stxt = (float*)(chreg + 18825216);      //    315,392
    int* idx_i = (int*)(chreg + 19140608);         //     65,536
    int* idx_t = (int*)(chreg + 19206144);         //     65,536
    // chunk-time pointers
    unsigned short* qn = (unsigned short*)chreg;                      // 17408*C B
    unsigned short* qkvQ = (unsigned short*)(chreg + (size_t)17408 * C);
    unsigned short* qkvKV = (unsigned short*)(chreg + (size_t)34816 * C);
    unsigned short* atto = (unsigned short*)(chreg + (size_t)69632 * C);
    unsigned short* hbuf = qkvQ;  // 69632*C B, overlays qkvQ+qkvKV+atto
    unsigned short* qn0 = atto;   // layer-0 folded LN1 output (nch==1 only)
    float* q = (float*)d_out;
    int fold = (nch == 1) ? 1 : 0;

    // weights -> bf16 (Wkv columns scaled by ln2_w); effective kv bias
    k_f2b4<<<3072, 256, 0, stream>>>(in_proj_w, out_w, fc_w, proj_w, ln2_w, wbf);
    k_bias2<<<512, 256, 0, stream>>>(in_proj_w, in_proj_b, ln2_b, b2eff);

    // token normalize
    k_l2norm<<<6272, 256, 0, stream>>>(image_tokens, img_n);
    k_l2norm<<<2464, 256, 0, stream>>>(text_tokens, txt_n);

    // factored score vectors
    k_colsum<<<32, 512, 0, stream>>>(img_n, nullptr, isum, 196);
    k_colsum<<<32, 512, 0, stream>>>(txt_n, atte_mask, tmask, 77);

    // scores + top-k + gather (q f32 + normalized kn + folded layer-0 qn)
    k_scores<<<1024, 256, 0, stream>>>(img_n, tmask, simg, 196, 0);
    k_scores<<<1024, 256, 0, stream>>>(txt_n, isum, stxt, 77, 1);
    k_topk<<<2048, 64, 0, stream>>>(simg, stxt, idx_i, idx_t);
    k_gather<<<69632, 64, 0, stream>>>(img_n, txt_n, image_feature, text_feature,
                                       img_cls, txt_cls, idx_i, idx_t,
                                       ln1_w, ln1_b, q, kstream, qn0, fold);

    // 2-layer cross-attention transformer, chunked over sequences
    for (int ch = 0; ch < nch; ch++) {
        size_t r0 = (size_t)ch * C * 17;
        float* qc = q + r0 * 512;
        const unsigned short* kc = kstream + r0 * 512;
        int rowsC = 17 * C;
        int gmt = rowsC / 128;  // M-tiles
        int gln = rowsC / 4;    // LN blocks (4 rows each)
        for (int l = 0; l < 2; l++) {
            const unsigned short* Wq = w_inproj + (size_t)l * 786432;
            const unsigned short* Wkv = Wq + 262144;
            const float* bq = in_proj_b + l * 1536;
            const unsigned short* Aq;
            if (l == 0 && fold) {
                Aq = qn0;  // gather wrote LN1_0 output
            } else {
                k_ln<<<gln, 256, 0, stream>>>(qc, ln1_w + l * 512, ln1_b + l * 512, qn);
                Aq = qn;
            }
            k_gemm<0><<<gmt * 4, 256, 0, stream>>>(Aq, Wq, bq, qkvQ, 512, 512, 4);
            k_gemm<0><<<gmt * 8, 256, 0, stream>>>(kc, Wkv, b2eff + l * 1024, qkvKV,
                                                   512, 1024, 8);
            k_attn<<<C, 512, 0, stream>>>(qkvQ, qkvKV, atto);
            k_gemm<2><<<gmt * 4, 256, 0, stream>>>(atto, w_outp + (size_t)l * 262144,
                                                   out_b + l * 512, qc, 512, 512, 4);
            k_ln<<<gln, 256, 0, stream>>>(qc, ln3_w + l * 512, ln3_b + l * 512, qn);
            k_gemm<1><<<gmt * 16, 256, 0, stream>>>(qn, w_fc + (size_t)l * 1048576,
                                                    fc_b + l * 2048, hbuf, 512, 2048, 16);
            k_gemm<2><<<gmt * 4, 256, 0, stream>>>(hbuf, w_proj + (size_t)l * 1048576,
                                                   proj_b + l * 512, qc, 2048, 512, 4);
        }
    }
}